// Round 15
// baseline (93.936 us; speedup 1.0000x reference)
//
#include <hip/hip_runtime.h>
#include <stdint.h>

typedef unsigned short u16;

#define B_ 8
#define C_ 64
#define H_ 128
#define W_ 128
#define OC_ 64
#define HO_ 128
#define WO_ 128
#define HWC_ (H_*W_*C_)   // elems per batch in NHWC

typedef __attribute__((ext_vector_type(8))) _Float16 f16x8;
typedef __attribute__((ext_vector_type(2))) _Float16 h2;
typedef __attribute__((ext_vector_type(4))) float f32x4;

__device__ __forceinline__ u16 f2h(float f) {
  union { _Float16 h; u16 u; } c; c.h = (_Float16)f; return c.u;
}
__device__ __forceinline__ uint32_t pkh2(float f) {   // (h,h) packed pair
  union { _Float16 h[2]; uint32_t u; } c;
  const _Float16 h = (_Float16)f;
  c.h[0] = h; c.h[1] = h; return c.u;
}

// ---- prep 1: weight [OC][C][3][3] f32 -> wk3 in MFMA A-fragment order (f16) ----
// flat = (((k*4 + m)*2 + kk)*64 + lane)*8 + j
//   oc = m*16 + (lane&15);  c = kk*32 + (lane>>4)*8 + j
__global__ void wprep_kernel(const float* __restrict__ w, u16* __restrict__ wk3) {
  const int idx = blockIdx.x * 256 + threadIdx.x;   // 144*256 = 36864 exact
  const int j    = idx & 7;
  const int lane = (idx >> 3) & 63;
  const int kk   = (idx >> 9) & 1;
  const int m    = (idx >> 10) & 3;
  const int k    = idx >> 12;
  const int oc = m*16 + (lane & 15);
  const int c  = kk*32 + (lane >> 4)*8 + j;
  wk3[idx] = f2h(w[(oc*C_ + c)*9 + k]);
}

// ---- prep 2: input NCHW f32 -> NHWC f16 ----
__global__ __launch_bounds__(256) void nhwc_kernel(const float* __restrict__ in,
                                                   u16* __restrict__ nhwc) {
  __shared__ float t[64][65];
  const int b = blockIdx.z, h = blockIdx.y, w0 = blockIdx.x * 64;
  const int tid = threadIdx.x;
  for (int idx = tid; idx < 64*64; idx += 256) {
    int c = idx >> 6, w = idx & 63;
    t[w][c] = in[((b*C_ + c)*H_ + h)*W_ + w0 + w];
  }
  __syncthreads();
  for (int idx = tid; idx < 64*64; idx += 256) {
    int w = idx >> 6, c = idx & 63;
    nhwc[((b*H_ + h)*W_ + w0 + w)*C_ + c] = f2h(t[w][c]);
  }
}

// packed-f16 bilinear blend: 2 channels per call, 4 v_pk_fma_f16
__device__ __forceinline__ uint32_t blendh(uint32_t g00, uint32_t g01,
                                           uint32_t g10, uint32_t g11, uint4 w) {
  h2 s = __builtin_bit_cast(h2, g00) * __builtin_bit_cast(h2, w.x)
       + __builtin_bit_cast(h2, g01) * __builtin_bit_cast(h2, w.y)
       + __builtin_bit_cast(h2, g10) * __builtin_bit_cast(h2, w.z)
       + __builtin_bit_cast(h2, g11) * __builtin_bit_cast(h2, w.w);
  return __builtin_bit_cast(uint32_t, s);
}

// pinned 16B global load (cannot be sunk; no compiler waitcnt)
#define GLOAD4(dst, p) \
  asm volatile("global_load_dwordx4 %0, %1, off" : "=v"(dst) : "v"(p))
#define WAITV(n) { \
    asm volatile("s_waitcnt vmcnt(" #n ")" ::: "memory"); \
    __builtin_amdgcn_sched_barrier(0); }

// ---- main: 1-wave blocks, wave = 32px x 64oc. Register-direct B-frags
//      (gather lane layout == MFMA B layout), asm-pinned ping-pong gather
//      pipeline, counted vmcnt, ZERO barriers, ZERO col-LDS. ----
__global__ __launch_bounds__(64, 2) void mdconv_main(
    const float* __restrict__ offs, const float* __restrict__ mask,
    const float* __restrict__ bias, const u16* __restrict__ nhwc,
    const u16* __restrict__ wk3, float* __restrict__ out)
{
  __shared__ int2 pA[288];          // 2304 B  {base, dx|dy<<16}
  __shared__ uint4 pW[288];         // 4608 B  corner weights, packed (h,h) f16x2

  const int lane = threadIdx.x;     // 0..63
  // XCD-chunk swizzle: XCD n (= id%8) owns batch n entirely
  const uint32_t id = blockIdx.x;
  const uint32_t sid = (id & 7) * 512 + (id >> 3);
  const int b  = sid >> 9;
  const int p  = (sid >> 2) & 127;
  const int q0 = (sid & 3) * 32;

  // phase 1: per-(k,px) sampling params -> LDS (wave-coherent; no barrier)
  for (int item = lane; item < 288; item += 64) {
    const int k = item >> 5;
    const int px = item & 31;
    const int q = q0 + px;
    const int ky = k / 3, kx = k % 3;
    const float oy = offs[((b*18 + 2*k)*HO_ + p)*WO_ + q];
    const float ox = offs[((b*18 + 2*k + 1)*HO_ + p)*WO_ + q];
    const float mm = mask[((b*9 + k)*HO_ + p)*WO_ + q];
    const float py  = (float)(ky + p - 1) + oy;
    const float pxx = (float)(kx + q - 1) + ox;
    const float y0f = floorf(py), x0f = floorf(pxx);
    const int y0 = (int)y0f, x0 = (int)x0f;
    const int y1 = y0 + 1, x1 = x0 + 1;
    const float wy1 = py - y0f, wx1 = pxx - x0f;
    const float wy0 = 1.f - wy1, wx0 = 1.f - wx1;
    const bool vy0 = (y0 >= 0) & (y0 < H_);
    const bool vy1 = (y1 >= 0) & (y1 < H_);
    const bool vx0 = (x0 >= 0) & (x0 < W_);
    const bool vx1 = (x1 >= 0) & (x1 < W_);
    const float w00 = (vy0 & vx0) ? wy0*wx0*mm : 0.f;
    const float w01 = (vy0 & vx1) ? wy0*wx1*mm : 0.f;
    const float w10 = (vy1 & vx0) ? wy1*wx0*mm : 0.f;
    const float w11 = (vy1 & vx1) ? wy1*wx1*mm : 0.f;
    const int y0c = min(max(y0,0),H_-1), y1c = min(max(y1,0),H_-1);
    const int x0c = min(max(x0,0),W_-1), x1c = min(max(x1,0),W_-1);
    // invalid corners have zero weight, so clamped deltas are always safe
    const int dx = (x1c - x0c) * C_;        // 0 or 64
    const int dy = (y1c - y0c) * W_ * C_;   // 0 or 8192
    pA[item] = make_int2(b*HWC_ + (y0c*W_ + x0c)*C_, dx | (dy << 16));
    pW[item] = make_uint4(pkh2(w00), pkh2(w01), pkh2(w10), pkh2(w11));
  }
  asm volatile("s_waitcnt lgkmcnt(0)" ::: "memory");
  __builtin_amdgcn_sched_barrier(0);

  f32x4 acc[4][2];
  #pragma unroll
  for (int m = 0; m < 4; ++m)
    #pragma unroll
    for (int n = 0; n < 2; ++n)
      acc[m][n] = (f32x4){0.f,0.f,0.f,0.f};

  const int pxl = lane & 15;         // B-frag col = px within 16-group
  const int c8e = (lane >> 4) * 8;   // B-frag k-rows = 8-ch chunk

  uint4 g0[16], g1[16];              // ping-pong gather state
  uint4 af[8];                       // A-fragments for current k

  // issue 16 gathers for k: per n-half {4 corners x 2 c-chunks (s, s+32)}
#define ISSUE_G(k_, gbuf) { \
    _Pragma("unroll") \
    for (int n = 0; n < 2; ++n) { \
      const int pi = (k_)*32 + n*16 + pxl; \
      const int2 aa = pA[pi]; \
      const int dx = aa.y & 0xFFFF, dy = ((uint32_t)aa.y) >> 16; \
      const u16* s = nhwc + aa.x + c8e; \
      GLOAD4(gbuf[n*8 + 0], (const uint4*)(s)); \
      GLOAD4(gbuf[n*8 + 1], (const uint4*)(s + 32)); \
      GLOAD4(gbuf[n*8 + 2], (const uint4*)(s + dx)); \
      GLOAD4(gbuf[n*8 + 3], (const uint4*)(s + dx + 32)); \
      GLOAD4(gbuf[n*8 + 4], (const uint4*)(s + dy)); \
      GLOAD4(gbuf[n*8 + 5], (const uint4*)(s + dy + 32)); \
      GLOAD4(gbuf[n*8 + 6], (const uint4*)(s + dy + dx)); \
      GLOAD4(gbuf[n*8 + 7], (const uint4*)(s + dy + dx + 32)); \
    } }

#define ISSUE_A(k_) { \
    const u16* wg = wk3 + ((k_)*8) * 512 + lane*8; \
    _Pragma("unroll") \
    for (int i = 0; i < 8; ++i) GLOAD4(af[i], (const uint4*)(wg + i*512)); }

  // blend + MFMA for k using gbuf; WAn = literal vmcnt before MFMA (A landed)
#define BLEND_MFMA(k_, gbuf, WAITA) { \
    union { uint32_t u[4]; f16x8 v; } bf0, bf1; \
    _Pragma("unroll") \
    for (int n = 0; n < 2; ++n) { \
      const uint4 wv = pW[(k_)*32 + n*16 + pxl]; \
      const uint4 ga = gbuf[n*8 + 0], gb = gbuf[n*8 + 1]; \
      const uint4 gc = gbuf[n*8 + 2], gd = gbuf[n*8 + 3]; \
      const uint4 ge = gbuf[n*8 + 4], gf = gbuf[n*8 + 5]; \
      const uint4 gg = gbuf[n*8 + 6], gh = gbuf[n*8 + 7]; \
      bf0.u[0] = blendh(ga.x, gc.x, ge.x, gg.x, wv); \
      bf0.u[1] = blendh(ga.y, gc.y, ge.y, gg.y, wv); \
      bf0.u[2] = blendh(ga.z, gc.z, ge.z, gg.z, wv); \
      bf0.u[3] = blendh(ga.w, gc.w, ge.w, gg.w, wv); \
      bf1.u[0] = blendh(gb.x, gd.x, gf.x, gh.x, wv); \
      bf1.u[1] = blendh(gb.y, gd.y, gf.y, gh.y, wv); \
      bf1.u[2] = blendh(gb.z, gd.z, gf.z, gh.z, wv); \
      bf1.u[3] = blendh(gb.w, gd.w, gf.w, gh.w, wv); \
      if (n == 0) { WAITA; } \
      _Pragma("unroll") \
      for (int m = 0; m < 4; ++m) { \
        acc[m][n] = __builtin_amdgcn_mfma_f32_16x16x32_f16( \
            __builtin_bit_cast(f16x8, af[m*2]),     bf0.v, acc[m][n], 0, 0, 0); \
        acc[m][n] = __builtin_amdgcn_mfma_f32_16x16x32_f16( \
            __builtin_bit_cast(f16x8, af[m*2 + 1]), bf1.v, acc[m][n], 0, 0, 0); \
      } \
    } }

  // prologue
  ISSUE_G(0, g0);                 // outstanding: 16

  // region k (even k in g0, odd in g1):
  //   issue A(k)[8] -> 24; issue G(k+1)[16] -> 40
  //   WAITV(24): G(k) landed; blend(k); WAITV(16): A(k) landed; MFMA(k)
#define REGION_MAIN(k_, GCUR, GNXT) { \
    ISSUE_A(k_); \
    ISSUE_G((k_)+1, GNXT); \
    WAITV(24); \
    BLEND_MFMA(k_, GCUR, WAITV(16)); }

  // last region (k=8): outstanding at entry = 16 (G(8)); A(8) -> 24
#define REGION_LAST(k_, GCUR) { \
    ISSUE_A(k_); \
    WAITV(8); \
    BLEND_MFMA(k_, GCUR, WAITV(0)); }

  REGION_MAIN(0, g0, g1);
  REGION_MAIN(1, g1, g0);
  REGION_MAIN(2, g0, g1);
  REGION_MAIN(3, g1, g0);
  REGION_MAIN(4, g0, g1);
  REGION_MAIN(5, g1, g0);
  REGION_MAIN(6, g0, g1);
  REGION_MAIN(7, g1, g0);
  REGION_LAST(8, g0);

  // epilogue: C/D layout col=lane&15 (px), row=(lane>>4)*4+j (oc)
  #pragma unroll
  for (int m = 0; m < 4; ++m) {
    const int ocr = m*16 + (lane >> 4)*4;
    const float4 b4 = *(const float4*)(bias + ocr);
    #pragma unroll
    for (int n = 0; n < 2; ++n) {
      const int q = q0 + n*16 + pxl;
      #pragma unroll
      for (int j = 0; j < 4; ++j) {
        out[((b*OC_ + ocr + j)*HO_ + p)*WO_ + q] = acc[m][n][j] + ((const float*)&b4)[j];
      }
    }
  }
}

extern "C" void kernel_launch(void* const* d_in, const int* in_sizes, int n_in,
                              void* d_out, int out_size, void* d_ws, size_t ws_size,
                              hipStream_t stream) {
  const float* input  = (const float*)d_in[0];
  const float* offset = (const float*)d_in[1];
  const float* mask   = (const float*)d_in[2];
  const float* weight = (const float*)d_in[3];
  const float* bias   = (const float*)d_in[4];
  float* out = (float*)d_out;

  u16* nhwc = (u16*)d_ws;                              // 16 MB
  u16* wk3  = nhwc + (size_t)B_*H_*W_*C_;              // 72 KB

  hipLaunchKernelGGL(wprep_kernel, dim3(144), dim3(256), 0, stream, weight, wk3);
  hipLaunchKernelGGL(nhwc_kernel, dim3(2, 128, 8), dim3(256), 0, stream, input, nhwc);
  hipLaunchKernelGGL(mdconv_main, dim3(4096), dim3(64), 0, stream,
                     offset, mask, bias, nhwc, wk3, out);
}

// Round 16
// 53.791 us; speedup vs baseline: 1.7463x; 1.7463x over previous
//
#include <hip/hip_runtime.h>
#include <stdint.h>

typedef unsigned short u16;

#define B_ 8
#define C_ 64
#define H_ 128
#define W_ 128
#define OC_ 64
#define HO_ 128
#define WO_ 128
#define HWC_ (H_*W_*C_)   // elems per batch in NHWC
#define PADW 72           // padded clds row (f16): 144B, 16B-aligned

typedef __attribute__((ext_vector_type(8))) _Float16 f16x8;
typedef __attribute__((ext_vector_type(2))) _Float16 h2;
typedef __attribute__((ext_vector_type(4))) float f32x4;

__device__ __forceinline__ u16 f2h(float f) {
  union { _Float16 h; u16 u; } c; c.h = (_Float16)f; return c.u;
}
__device__ __forceinline__ uint32_t pkh2(float f) {   // (h,h) packed pair
  union { _Float16 h[2]; uint32_t u; } c;
  const _Float16 h = (_Float16)f;
  c.h[0] = h; c.h[1] = h; return c.u;
}

// ---- prep 1: weight [OC][C][3][3] f32 -> wk2 in MFMA A-fragment order (f16) ----
// wk2 flat index = (((k*2 + wr)*2 + m)*2 + kk)*512 + lane*8 + j
//   oc = wr*32 + m*16 + (lane&15);  c = kk*32 + (lane>>4)*8 + j
__global__ void wprep_kernel(const float* __restrict__ w, u16* __restrict__ wk2) {
  const int idx = blockIdx.x * 256 + threadIdx.x;   // 144*256 = 36864 exact
  const int j    = idx & 7;
  const int lane = (idx >> 3) & 63;
  const int kk   = (idx >> 9) & 1;
  const int m    = (idx >> 10) & 1;
  const int wr   = (idx >> 11) & 1;
  const int k    = idx >> 12;
  const int oc = wr*32 + m*16 + (lane & 15);
  const int c  = kk*32 + (lane >> 4)*8 + j;
  wk2[idx] = f2h(w[(oc*C_ + c)*9 + k]);
}

// ---- prep 2: input NCHW f32 -> NHWC f16 ----
__global__ __launch_bounds__(256) void nhwc_kernel(const float* __restrict__ in,
                                                   u16* __restrict__ nhwc) {
  __shared__ float t[64][65];
  const int b = blockIdx.z, h = blockIdx.y, w0 = blockIdx.x * 64;
  const int tid = threadIdx.x;
  for (int idx = tid; idx < 64*64; idx += 256) {
    int c = idx >> 6, w = idx & 63;
    t[w][c] = in[((b*C_ + c)*H_ + h)*W_ + w0 + w];
  }
  __syncthreads();
  for (int idx = tid; idx < 64*64; idx += 256) {
    int w = idx >> 6, c = idx & 63;
    nhwc[((b*H_ + h)*W_ + w0 + w)*C_ + c] = f2h(t[w][c]);
  }
}

// packed-f16 bilinear blend: 2 channels per call, 4 v_pk_fma_f16
__device__ __forceinline__ uint32_t blendh(uint32_t g00, uint32_t g01,
                                           uint32_t g10, uint32_t g11, uint4 w) {
  h2 s = __builtin_bit_cast(h2, g00) * __builtin_bit_cast(h2, w.x)
       + __builtin_bit_cast(h2, g01) * __builtin_bit_cast(h2, w.y)
       + __builtin_bit_cast(h2, g10) * __builtin_bit_cast(h2, w.z)
       + __builtin_bit_cast(h2, g11) * __builtin_bit_cast(h2, w.w);
  return __builtin_bit_cast(uint32_t, s);
}

// ---- main: 64px x 64oc per block (4 waves, halves weight re-reads vs 32px),
//      TWO k-steps per barrier region, XCD-chunk swizzle ----
__global__ __launch_bounds__(256, 4) void mdconv_main(
    const float* __restrict__ offs, const float* __restrict__ mask,
    const float* __restrict__ bias, const u16* __restrict__ nhwc,
    const u16* __restrict__ wk2, float* __restrict__ out)
{
  __shared__ u16 clds[2][64*PADW];  // 18432 B, one buffer per k of the pair
  __shared__ int2 pA[576];          //  4608 B  {base, dx|dy<<16}
  __shared__ uint4 pW[576];         //  9216 B  corner weights, packed (h,h) f16x2

  const int tid = threadIdx.x;      // 0..255
  const int lane = tid & 63;
  const int wv = tid >> 6;          // 0..3
  // XCD-chunk swizzle: XCD n (= id%8) owns batch n's 256 blocks contiguously
  const uint32_t id = blockIdx.x;
  const uint32_t sid = (id & 7) * 256 + (id >> 3);
  const int b  = sid >> 8;
  const int p  = (sid >> 1) & 127;
  const int q0 = (sid & 1) * 64;

  // phase 1: per-(k,px) sampling params -> LDS
  for (int item = tid; item < 576; item += 256) {
    const int k = item >> 6;
    const int px = item & 63;
    const int q = q0 + px;
    const int ky = k / 3, kx = k % 3;
    const float oy = offs[((b*18 + 2*k)*HO_ + p)*WO_ + q];
    const float ox = offs[((b*18 + 2*k + 1)*HO_ + p)*WO_ + q];
    const float mm = mask[((b*9 + k)*HO_ + p)*WO_ + q];
    const float py  = (float)(ky + p - 1) + oy;
    const float pxx = (float)(kx + q - 1) + ox;
    const float y0f = floorf(py), x0f = floorf(pxx);
    const int y0 = (int)y0f, x0 = (int)x0f;
    const int y1 = y0 + 1, x1 = x0 + 1;
    const float wy1 = py - y0f, wx1 = pxx - x0f;
    const float wy0 = 1.f - wy1, wx0 = 1.f - wx1;
    const bool vy0 = (y0 >= 0) & (y0 < H_);
    const bool vy1 = (y1 >= 0) & (y1 < H_);
    const bool vx0 = (x0 >= 0) & (x0 < W_);
    const bool vx1 = (x1 >= 0) & (x1 < W_);
    const float w00 = (vy0 & vx0) ? wy0*wx0*mm : 0.f;
    const float w01 = (vy0 & vx1) ? wy0*wx1*mm : 0.f;
    const float w10 = (vy1 & vx0) ? wy1*wx0*mm : 0.f;
    const float w11 = (vy1 & vx1) ? wy1*wx1*mm : 0.f;
    const int y0c = min(max(y0,0),H_-1), y1c = min(max(y1,0),H_-1);
    const int x0c = min(max(x0,0),W_-1), x1c = min(max(x1,0),W_-1);
    // invalid corners have zero weight, so clamped deltas are always safe
    const int dx = (x1c - x0c) * C_;        // 0 or 64
    const int dy = (y1c - y0c) * W_ * C_;   // 0 or 8192
    pA[item] = make_int2(b*HWC_ + (y0c*W_ + x0c)*C_, dx | (dy << 16));
    pW[item] = make_uint4(pkh2(w00), pkh2(w01), pkh2(w10), pkh2(w11));
  }
  __syncthreads();

  f32x4 acc00 = {0.f,0.f,0.f,0.f};
  f32x4 acc01 = acc00, acc10 = acc00, acc11 = acc00;
  const int wr = wv >> 1, wc = wv & 1;
  const int px0 = tid >> 3;          // 0..31 (second item: +32)
  const int c8 = (tid & 7) * 8;      // channel chunk start

#define COLB(k_, buf_) { \
    const int piA = (k_)*64 + px0, piB = piA + 32; \
    const int2 aA = pA[piA]; const int2 aB = pA[piB]; \
    const uint4 wA = pW[piA]; const uint4 wB = pW[piB]; \
    const u16* sA = nhwc + aA.x + c8; \
    const u16* sB = nhwc + aB.x + c8; \
    const int dxA = aA.y & 0xFFFF, dyA = ((uint32_t)aA.y) >> 16; \
    const int dxB = aB.y & 0xFFFF, dyB = ((uint32_t)aB.y) >> 16; \
    const uint4 gA00 = *(const uint4*)(sA); \
    const uint4 gA01 = *(const uint4*)(sA + dxA); \
    const uint4 gA10 = *(const uint4*)(sA + dyA); \
    const uint4 gA11 = *(const uint4*)(sA + dyA + dxA); \
    const uint4 gB00 = *(const uint4*)(sB); \
    const uint4 gB01 = *(const uint4*)(sB + dxB); \
    const uint4 gB10 = *(const uint4*)(sB + dyB); \
    const uint4 gB11 = *(const uint4*)(sB + dyB + dxB); \
    uint4 rA, rB; \
    rA.x = blendh(gA00.x, gA01.x, gA10.x, gA11.x, wA); \
    rA.y = blendh(gA00.y, gA01.y, gA10.y, gA11.y, wA); \
    rA.z = blendh(gA00.z, gA01.z, gA10.z, gA11.z, wA); \
    rA.w = blendh(gA00.w, gA01.w, gA10.w, gA11.w, wA); \
    rB.x = blendh(gB00.x, gB01.x, gB10.x, gB11.x, wB); \
    rB.y = blendh(gB00.y, gB01.y, gB10.y, gB11.y, wB); \
    rB.z = blendh(gB00.z, gB01.z, gB10.z, gB11.z, wB); \
    rB.w = blendh(gB00.w, gB01.w, gB10.w, gB11.w, wB); \
    *(uint4*)(&clds[buf_][px0*PADW + c8]) = rA; \
    *(uint4*)(&clds[buf_][(px0+32)*PADW + c8]) = rB; }

#define MFMA8(k_, buf_) { \
    const u16* wg = wk2 + ((k_)*2 + wr)*2048 + lane*8; \
    const f16x8 a00 = *(const f16x8*)(wg); \
    const f16x8 a01 = *(const f16x8*)(wg + 512); \
    const f16x8 a10 = *(const f16x8*)(wg + 1024); \
    const f16x8 a11 = *(const f16x8*)(wg + 1536); \
    const u16* cb = &clds[buf_][(wc*32 + (lane & 15))*PADW + (lane >> 4)*8]; \
    const f16x8 b00 = *(const f16x8*)(cb); \
    const f16x8 b01 = *(const f16x8*)(cb + 32); \
    const f16x8 b10 = *(const f16x8*)(cb + 16*PADW); \
    const f16x8 b11 = *(const f16x8*)(cb + 16*PADW + 32); \
    acc00 = __builtin_amdgcn_mfma_f32_16x16x32_f16(a00, b00, acc00, 0, 0, 0); \
    acc00 = __builtin_amdgcn_mfma_f32_16x16x32_f16(a01, b01, acc00, 0, 0, 0); \
    acc01 = __builtin_amdgcn_mfma_f32_16x16x32_f16(a00, b10, acc01, 0, 0, 0); \
    acc01 = __builtin_amdgcn_mfma_f32_16x16x32_f16(a01, b11, acc01, 0, 0, 0); \
    acc10 = __builtin_amdgcn_mfma_f32_16x16x32_f16(a10, b00, acc10, 0, 0, 0); \
    acc10 = __builtin_amdgcn_mfma_f32_16x16x32_f16(a11, b01, acc10, 0, 0, 0); \
    acc11 = __builtin_amdgcn_mfma_f32_16x16x32_f16(a10, b10, acc11, 0, 0, 0); \
    acc11 = __builtin_amdgcn_mfma_f32_16x16x32_f16(a11, b11, acc11, 0, 0, 0); }

  // 4 double-k regions + 1 single-k region: 10 barriers total
  for (int r = 0; r < 4; ++r) {
    const int k0 = 2*r;
    COLB(k0, 0);
    COLB(k0 + 1, 1);
    __syncthreads();
    MFMA8(k0, 0);
    MFMA8(k0 + 1, 1);
    __syncthreads();
  }
  COLB(8, 0);
  __syncthreads();
  MFMA8(8, 0);

  // epilogue: C/D layout col=lane&15 (px), row=(lane>>4)*4+j (oc)
  const int qc = q0 + wc*32 + (lane & 15);
  const int ocr = wr*32 + (lane >> 4)*4;
  #pragma unroll
  for (int m = 0; m < 2; ++m) {
    #pragma unroll
    for (int n = 0; n < 2; ++n) {
      const f32x4 a = (m==0) ? (n==0 ? acc00 : acc01) : (n==0 ? acc10 : acc11);
      #pragma unroll
      for (int j = 0; j < 4; ++j) {
        const int oc = ocr + m*16 + j;
        out[((b*OC_ + oc)*HO_ + p)*WO_ + qc + n*16] = a[j] + bias[oc];
      }
    }
  }
}

extern "C" void kernel_launch(void* const* d_in, const int* in_sizes, int n_in,
                              void* d_out, int out_size, void* d_ws, size_t ws_size,
                              hipStream_t stream) {
  const float* input  = (const float*)d_in[0];
  const float* offset = (const float*)d_in[1];
  const float* mask   = (const float*)d_in[2];
  const float* weight = (const float*)d_in[3];
  const float* bias   = (const float*)d_in[4];
  float* out = (float*)d_out;

  u16* nhwc = (u16*)d_ws;                              // 16 MB
  u16* wk2  = nhwc + (size_t)B_*H_*W_*C_;              // 72 KB

  hipLaunchKernelGGL(wprep_kernel, dim3(144), dim3(256), 0, stream, weight, wk2);
  hipLaunchKernelGGL(nhwc_kernel, dim3(2, 128, 8), dim3(256), 0, stream, input, nhwc);
  hipLaunchKernelGGL(mdconv_main, dim3(2048), dim3(256), 0, stream,
                     offset, mask, bias, nhwc, wk2, out);
}